// Round 6
// baseline (586.549 us; speedup 1.0000x reference)
//
#include <hip/hip_runtime.h>

#define B_ 32
#define T_ 1024
#define C_ 384
#define MAXLEN_ 2048
#define NBINS_ 255
#define WPK1 442368          /* 36*4*6*512 packed bf16 elems per weight */
#define BTC  (32 * 1024 * 384)
#define ARS 396              /* A-tile row stride in bf16; lane stride 6 mod 32 banks */

typedef __attribute__((ext_vector_type(8))) short short8v;   // 8 bf16 = 4 VGPRs
typedef __attribute__((ext_vector_type(4))) float floatx4;

__device__ __forceinline__ unsigned short f2bf(float f) {
    unsigned u = __float_as_uint(f);
    u += 0x7fffu + ((u >> 16) & 1u);   // RNE
    return (unsigned short)(u >> 16);
}

struct CvP {
    const float* xf;              // layer1 input (fp32 x)
    const unsigned short* xb;     // layer2 input base (h1b), + p*BTC
    const unsigned short* wpk;    // + p*WPK1
    const float* bias[3];
    const float* gamma[3];
    const float* beta[3];
    const float* wo[3];
    const float* bo[3];
    unsigned short* hout;         // layer1 out, + p*BTC
    float* pred[3];               // layer2 out
    const float* pbins;           // pitch-emb fusion (layer1, p==2)
    const float* pemb;
    const float* ptgt;
    int final_flag;
};

// ---------------------------------------------------------------------------
// 3-predictor fused conv1d(K=3,SAME)+bias+relu+LN[+projection], bf16 MFMA.
// Block: 256 thr = 4 waves, tile 64 rows x 384 cols; wave owns 96 cols.
// Register budget engineered for 3 waves/SIMD (the R3/R4/R5 plateau was
// 2 waves/SIMD latency-starvation): acc 96 AGPR + B single rolling buffer
// 24 VGPR + afrag 16. B reloaded per-fragment right after last use
// (distance-1, MFMA<->load 1:1 interleave). LDS 52.3 KB -> 3 blocks/CU.
// ---------------------------------------------------------------------------
__global__ __launch_bounds__(256, 3) void conv_mfma3(CvP P)
{
    __shared__ unsigned short As[66 * ARS];   // 52.3 KB
    float* rsum = (float*)As;                 // [4][64] aliased (post-K-loop)
    float* rsq  = rsum + 256;

    const int tid  = threadIdx.x;
    const int wave = tid >> 6;      // col group 0..3
    const int lane = tid & 63;
    const int lq   = lane >> 4;
    const int ln   = lane & 15;
    const int p    = blockIdx.x >> 9;       // predictor 0..2
    const int bi   = blockIdx.x & 511;      // tile 0..511
    const int b    = bi >> 4;
    const int t0   = (bi & 15) << 6;        // 64-row tiles
    const int nb   = wave * 96;

    // ---- B prefetch, step 0 (issued before staging to hide latency)
    const unsigned short* bbase =
        P.wpk + (size_t)p * WPK1 + wave * 3072 + (size_t)lane * 8;
    short8v bcur[6];
#pragma unroll
    for (int nt = 0; nt < 6; ++nt)
        bcur[nt] = *(const short8v*)(bbase + (nt << 9));

    // ---- stage A-tile rows t0-1 .. t0+64 (zero halo) ----
    if (!P.final_flag) {
        // layer1: cast fp32 x -> bf16; p==2 additionally adds pitch emb
        const bool fuse_emb = (p == 2);
        for (int i = tid; i < 66 * 48; i += 256) {
            const int row = i / 48;
            const int c   = i - row * 48;
            const int t   = t0 - 1 + row;
            short8v v = (short8v){0,0,0,0,0,0,0,0};
            if ((unsigned)t < (unsigned)T_) {
                const float* sp = P.xf + ((size_t)(b << 10) + t) * C_ + c * 8;
                float f[8];
                *(float4*)&f[0] = *(const float4*)sp;
                *(float4*)&f[4] = *(const float4*)(sp + 4);
                if (fuse_emb) {
                    const float tg = P.ptgt[(b << 10) + t];
                    int lo = 0, hi = NBINS_;
                    while (lo < hi) {
                        const int mid = (lo + hi) >> 1;
                        if (P.pbins[mid] < tg) lo = mid + 1; else hi = mid;
                    }
                    const float* er = P.pemb + (size_t)lo * C_ + c * 8;
#pragma unroll
                    for (int j = 0; j < 8; ++j) f[j] += er[j];
                }
#pragma unroll
                for (int j = 0; j < 8; ++j) v[j] = (short)f2bf(f[j]);
            }
            *(short8v*)&As[row * ARS + c * 8] = v;
        }
    } else {
        const unsigned short* xb = P.xb + (size_t)p * BTC;
        for (int i = tid; i < 66 * 48; i += 256) {
            const int row = i / 48;
            const int c   = i - row * 48;
            const int t   = t0 - 1 + row;
            short8v v = (short8v){0,0,0,0,0,0,0,0};
            if ((unsigned)t < (unsigned)T_)
                v = *(const short8v*)(xb + ((size_t)(b << 10) + t) * C_ + c * 8);
            *(short8v*)&As[row * ARS + c * 8] = v;
        }
    }
    __syncthreads();

    floatx4 acc[24];
#pragma unroll
    for (int i = 0; i < 24; ++i) acc[i] = (floatx4){0.f, 0.f, 0.f, 0.f};

    // single LDS vaddr; all K-loop offsets are compile-time immediates
    const unsigned short* abase = &As[ln * ARS + lq * 8];
    const unsigned short* bp = bbase + 12288;   // step 1 base

#pragma unroll
    for (int kc = 0; kc < 3; ++kc) {
#pragma unroll
        for (int hh = 0; hh < 12; ++hh) {
            const int r  = kc * 12 + hh;
            const int hb = hh * 32;
            short8v afrag[4];
#pragma unroll
            for (int mt = 0; mt < 4; ++mt)
                afrag[mt] = *(const short8v*)(abase + (mt * 16 + kc) * ARS + hb);
            // nt-outer: consume bcur[nt], then immediately reload it for
            // the next step (rolling distance-1 prefetch, 1:1 interleave)
#pragma unroll
            for (int nt = 0; nt < 6; ++nt) {
#pragma unroll
                for (int mt = 0; mt < 4; ++mt)
                    acc[mt * 6 + nt] = __builtin_amdgcn_mfma_f32_16x16x32_bf16(
                        afrag[mt], bcur[nt], acc[mt * 6 + nt], 0, 0, 0);
                if (r + 1 < 36)
                    bcur[nt] = *(const short8v*)(bp + (nt << 9));
            }
            bp += 12288;
        }
    }
    __syncthreads();   // all As reads done before aliasing it as rsum/rsq

    // ---- epilogue: bias+relu, LN over 384 cols/row ----
    float bcol[6], gcol[6], becol[6], wcol[6];
#pragma unroll
    for (int nt = 0; nt < 6; ++nt) {
        const int col = nb + nt * 16 + ln;
        bcol[nt]  = P.bias[p][col];
        gcol[nt]  = P.gamma[p][col];
        becol[nt] = P.beta[p][col];
        wcol[nt]  = P.final_flag ? P.wo[p][col] : 0.f;
    }

#pragma unroll
    for (int mt = 0; mt < 4; ++mt) {
#pragma unroll
        for (int rg = 0; rg < 4; ++rg) {
            float s = 0.f, q = 0.f;
#pragma unroll
            for (int nt = 0; nt < 6; ++nt) {
                float v = acc[mt * 6 + nt][rg] + bcol[nt];
                v = v > 0.f ? v : 0.f;
                acc[mt * 6 + nt][rg] = v;
                s += v; q += v * v;
            }
#pragma unroll
            for (int off = 1; off < 16; off <<= 1) {
                s += __shfl_xor(s, off, 64);
                q += __shfl_xor(q, off, 64);
            }
            if (ln == mt * 4 + rg) {
                rsum[wave * 64 + mt * 16 + lq * 4 + rg] = s;
                rsq [wave * 64 + mt * 16 + lq * 4 + rg] = q;
            }
        }
    }
    __syncthreads();

    float mean_[16], rstd_[16];
#pragma unroll
    for (int mt = 0; mt < 4; ++mt) {
#pragma unroll
        for (int rg = 0; rg < 4; ++rg) {
            const int row = mt * 16 + lq * 4 + rg;
            const float s = rsum[row] + rsum[64 + row] + rsum[128 + row] + rsum[192 + row];
            const float q = rsq[row] + rsq[64 + row] + rsq[128 + row] + rsq[192 + row];
            const float m = s * (1.f / 384.f);
            const float var = q * (1.f / 384.f) - m * m;
            mean_[mt * 4 + rg] = m;
            rstd_[mt * 4 + rg] = rsqrtf(var + 1e-5f);
        }
    }

    if (!P.final_flag) {
        unsigned short* hout = P.hout + (size_t)p * BTC;
#pragma unroll
        for (int mt = 0; mt < 4; ++mt)
#pragma unroll
            for (int rg = 0; rg < 4; ++rg) {
                const float m = mean_[mt * 4 + rg], rs = rstd_[mt * 4 + rg];
                const int grow = (bi << 6) + mt * 16 + lq * 4 + rg;
#pragma unroll
                for (int nt = 0; nt < 6; ++nt) {
                    const float v = (acc[mt * 6 + nt][rg] - m) * rs * gcol[nt] + becol[nt];
                    hout[(size_t)grow * C_ + nb + nt * 16 + ln] = f2bf(v);
                }
            }
    } else {
        __syncthreads();                       // rsum about to be reused
#pragma unroll
        for (int mt = 0; mt < 4; ++mt) {
#pragma unroll
            for (int rg = 0; rg < 4; ++rg) {
                const float m = mean_[mt * 4 + rg], rs = rstd_[mt * 4 + rg];
                float pr = 0.f;
#pragma unroll
                for (int nt = 0; nt < 6; ++nt)
                    pr += ((acc[mt * 6 + nt][rg] - m) * rs * gcol[nt] + becol[nt]) * wcol[nt];
#pragma unroll
                for (int off = 1; off < 16; off <<= 1)
                    pr += __shfl_xor(pr, off, 64);
                if (ln == mt * 4 + rg)
                    rsum[wave * 64 + mt * 16 + lq * 4 + rg] = pr;
            }
        }
        __syncthreads();
        if (tid < 64)
            P.pred[p][(bi << 6) + tid] =
                rsum[tid] + rsum[64 + tid] + rsum[128 + tid] + rsum[192 + tid] + P.bo[p][0];
    }
}

// w (1152,384) fp32 -> wpk fragment-major bf16:
// wpk[((r*4+wv)*6+nt)*512 + lane*8 + j] = w[(r*32 + (lane>>4)*8 + j)*384 +
//                                          wv*96 + nt*16 + (lane&15)]
__global__ __launch_bounds__(256) void pack_w_kernel(
    const float* __restrict__ s0, const float* __restrict__ s1,
    const float* __restrict__ s2, const float* __restrict__ s3,
    const float* __restrict__ s4, const float* __restrict__ s5,
    unsigned short* __restrict__ dst)
{
    const int wsel = blockIdx.y;
    const float* src = wsel == 0 ? s0 : wsel == 1 ? s1 : wsel == 2 ? s2
                     : wsel == 3 ? s3 : wsel == 4 ? s4 : s5;
    const int o = blockIdx.x * 256 + threadIdx.x;   // 442368
    const int r    = o / 12288;
    const int rem  = o - r * 12288;
    const int wv   = rem / 3072;
    const int rem2 = rem - wv * 3072;
    const int nt   = rem2 >> 9;
    const int li   = rem2 & 511;
    const int lane = li >> 3;
    const int j    = li & 7;
    const int n = wv * 96 + nt * 16 + (lane & 15);
    const int k = ((lane >> 4) << 3) + j;
    dst[(size_t)wsel * WPK1 + o] = f2bf(src[(size_t)(r * 32 + k) * C_ + n]);
}

// per-batch inclusive cumsum of duration (T=1024) + mel_len
__global__ __launch_bounds__(256) void cumsum_kernel(
    const int* __restrict__ dur, int* __restrict__ csum,
    float* __restrict__ mel_len)
{
    __shared__ int part[256];
    const int b = blockIdx.x;
    const int tid = threadIdx.x;
    int l[4];
    int s = 0;
#pragma unroll
    for (int i = 0; i < 4; ++i) { l[i] = dur[b * T_ + tid * 4 + i]; s += l[i]; }
    part[tid] = s;
    __syncthreads();
    for (int off = 1; off < 256; off <<= 1) {
        int u = 0;
        if (tid >= off) u = part[tid - off];
        __syncthreads();
        part[tid] += u;
        __syncthreads();
    }
    const int incl = part[tid];
    int run = incl - s;
#pragma unroll
    for (int i = 0; i < 4; ++i) {
        run += l[i];
        csum[b * T_ + tid * 4 + i] = run;
    }
    if (tid == 255) mel_len[b] = (float)incl;
}

// out[b,frame,:] = valid ? x[b,t,:] + pemb[pi(b,t)] + eemb[ei(b,t)] : 0  (fp32 exact)
__global__ __launch_bounds__(256) void length_reg_kernel(
    const float* __restrict__ x, const int* __restrict__ csum,
    const float* __restrict__ pbins, const float* __restrict__ pemb,
    const float* __restrict__ ptgt,
    const float* __restrict__ ebins, const float* __restrict__ eemb,
    const float* __restrict__ etgt,
    float* __restrict__ out)
{
    const int g    = blockIdx.x * 256 + threadIdx.x;  // B*2048*96
    const int c4   = g % 96;
    const int rest = g / 96;
    const int frame = rest & (MAXLEN_ - 1);
    const int b     = rest >> 11;
    const int* cr = csum + (b << 10);
    const int total = cr[T_ - 1];
    float4 v = make_float4(0.f, 0.f, 0.f, 0.f);
    if (frame < total) {
        int lo = 0, hi = T_;
        while (lo < hi) {
            const int mid = (lo + hi) >> 1;
            if (cr[mid] <= frame) lo = mid + 1; else hi = mid;
        }
        const int t = lo > T_ - 1 ? T_ - 1 : lo;
        const int row = (b << 10) + t;
        v = *(const float4*)(x + (size_t)row * C_ + c4 * 4);
        const float ptg = ptgt[row];
        int plo = 0, phi = NBINS_;
        while (plo < phi) {
            const int mid = (plo + phi) >> 1;
            if (pbins[mid] < ptg) plo = mid + 1; else phi = mid;
        }
        const float etg = etgt[row];
        int elo = 0, ehi = NBINS_;
        while (elo < ehi) {
            const int mid = (elo + ehi) >> 1;
            if (ebins[mid] < etg) elo = mid + 1; else ehi = mid;
        }
        const float4 pe = *(const float4*)(pemb + (size_t)plo * C_ + c4 * 4);
        const float4 ee = *(const float4*)(eemb + (size_t)elo * C_ + c4 * 4);
        v.x += pe.x + ee.x; v.y += pe.y + ee.y;
        v.z += pe.z + ee.z; v.w += pe.w + ee.w;
    }
    *(float4*)(out + (size_t)g * 4) = v;
}

extern "C" void kernel_launch(void* const* d_in, const int* in_sizes, int n_in,
                              void* d_out, int out_size, void* d_ws, size_t ws_size,
                              hipStream_t stream)
{
    const float* x        = (const float*)d_in[0];
    const int*   duration = (const int*)d_in[2];
    const float* P[3][10];
    for (int p = 0; p < 3; ++p)
        for (int q = 0; q < 10; ++q)
            P[p][q] = (const float*)d_in[4 + p * 10 + q];
    const float* pitch_bins    = (const float*)d_in[34];
    const float* energy_bins   = (const float*)d_in[35];
    const float* pitch_emb     = (const float*)d_in[36];
    const float* energy_emb    = (const float*)d_in[37];
    const float* pitch_target  = (const float*)d_in[38];
    const float* energy_target = (const float*)d_in[39];

    float* out_x      = (float*)d_out;                       // (B,2048,384)
    float* out_pitch  = out_x + (size_t)B_ * MAXLEN_ * C_;
    float* out_energy = out_pitch + B_ * T_;
    float* out_logdur = out_energy + B_ * T_;
    float* out_mellen = out_logdur + B_ * T_;

    // h1b (3 predictors, bf16) lives in the x_out region (75.5 MB of 100.7 MB,
    // dead before length_reg writes it)
    unsigned short* h1b = (unsigned short*)out_x;

    unsigned short* wpk = (unsigned short*)d_ws;             // 6*WPK1 bf16
    int* csum = (int*)(wpk + (size_t)6 * WPK1);

    const dim3 blk(256);

    pack_w_kernel<<<dim3(1728, 6), blk, 0, stream>>>(
        P[0][0], P[0][4], P[1][0], P[1][4], P[2][0], P[2][4], wpk);

    CvP P1;
    P1.xf = x; P1.xb = nullptr; P1.wpk = wpk;
    for (int p = 0; p < 3; ++p) {
        P1.bias[p]  = P[p][1];
        P1.gamma[p] = P[p][2];
        P1.beta[p]  = P[p][3];
        P1.wo[p]    = nullptr;
        P1.bo[p]    = nullptr;
        P1.pred[p]  = nullptr;
    }
    P1.hout = h1b;
    P1.pbins = pitch_bins; P1.pemb = pitch_emb; P1.ptgt = pitch_target;
    P1.final_flag = 0;

    CvP P2;
    P2.xf = nullptr; P2.xb = h1b; P2.wpk = wpk + (size_t)3 * WPK1;
    for (int p = 0; p < 3; ++p) {
        P2.bias[p]  = P[p][5];
        P2.gamma[p] = P[p][6];
        P2.beta[p]  = P[p][7];
        P2.wo[p]    = P[p][8];
        P2.bo[p]    = P[p][9];
    }
    P2.pred[0] = out_logdur; P2.pred[1] = out_pitch; P2.pred[2] = out_energy;
    P2.hout = nullptr;
    P2.pbins = nullptr; P2.pemb = nullptr; P2.ptgt = nullptr;
    P2.final_flag = 1;

    conv_mfma3<<<1536, blk, 0, stream>>>(P1);
    conv_mfma3<<<1536, blk, 0, stream>>>(P2);

    cumsum_kernel<<<B_, blk, 0, stream>>>(duration, csum, out_mellen);
    length_reg_kernel<<<24576, blk, 0, stream>>>(
        x, csum, pitch_bins, pitch_emb, pitch_target,
        energy_bins, energy_emb, energy_target, out_x);
}